// Round 2
// baseline (426.891 us; speedup 1.0000x reference)
//
#include <hip/hip_runtime.h>

#define NB 64      // batch
#define NC 32      // channels
#define PLANE 256  // 16*16
#define NK 4096    // codebook size

// ---------------- cubic (Keys a=-0.5), matches jax.image.resize 'cubic' ----
__device__ __forceinline__ float cubic_w(float x) {
    x = fabsf(x);
    if (x >= 2.f) return 0.f;
    if (x >= 1.f) return ((-0.5f * x + 2.5f) * x - 4.f) * x + 2.f;
    return ((1.5f * x - 2.5f) * x) * x + 1.f;
}

// taps for upsampling PN -> 16, jax convention: sample_f=(o+0.5)*PN/16-0.5,
// weights over in-range input idx, normalized by their sum (border renorm).
template <int PN>
__device__ __forceinline__ void taps(int o, float* w, int& i0, int& n) {
    float sf = (o + 0.5f) * ((float)PN / 16.f) - 0.5f;
    int lo = (int)floorf(sf) - 1;
    int hi = lo + 3;
    if (lo < 0) lo = 0;
    if (hi > PN - 1) hi = PN - 1;
    n = hi - lo + 1;
    i0 = lo;
    float tot = 0.f;
    for (int i = 0; i < n; i++) {
        float ww = cubic_w(sf - (float)(lo + i));
        w[i] = ww;
        tot += ww;
    }
    float inv = 1.f / tot;
    for (int i = 0; i < n; i++) w[i] *= inv;
}

// ---------------- init: plane means of z_enc -> zflat0 ; ||e||^2 -----------
__global__ void __launch_bounds__(256) init_kernel(
    const float* __restrict__ z_enc, const float* __restrict__ emb,
    float* __restrict__ zflat0, float* __restrict__ wsq) {
    int bc = blockIdx.x;           // b*32 + c, 0..2047
    int t = threadIdx.x;           // pixel in plane
    float v = z_enc[bc * PLANE + t];
    for (int o = 32; o > 0; o >>= 1) v += __shfl_down(v, o, 64);
    __shared__ float p[4];
    if ((t & 63) == 0) p[t >> 6] = v;
    __syncthreads();
    if (t == 0) zflat0[bc] = (p[0] + p[1] + p[2] + p[3]) * (1.f / 256.f);
    // two wsq entries per block (wsq is tiny magnitude ~3e-3: association
    // differences are ~1e-10, far below the dist grid -> tree reduce is fine)
    if (t < 64) {
        int k = 2 * bc + (t >> 5);
        int c = t & 31;
        float e = emb[k * 32 + c];
        float s = __fmul_rn(e, e);
        for (int o = 16; o > 0; o >>= 1) s += __shfl_down(s, o, 32);
        if (c == 0) wsq[k] = s;
    }
}

// ---------------- argmin partial: 1 wave = 64 tokens, wave-uniform k loop ---
// dist computed EXACTLY like the numpy reference: fl(fl(zsq+wsq[k]) - 2*dot),
// dot = sequential fp32 FMA chain over c (BLAS sgemm order). This reproduces
// the reference's coarse (ulp~2e-6 at mag 32) rounding grid and its ties.
__global__ void __launch_bounds__(64) part_kernel(
    const float* __restrict__ zflat, const float* __restrict__ emb,
    const float* __restrict__ wsq, float* __restrict__ cand_d,
    int* __restrict__ cand_i, int T, int CPK) {
    int tok = blockIdx.x * 64 + threadIdx.x;
    int ks = blockIdx.y;
    int k0 = ks * CPK;
    float z[32];
    const float4* zr = (const float4*)(zflat + (size_t)tok * 32);
#pragma unroll
    for (int q = 0; q < 8; q++) {
        float4 v = zr[q];
        z[4 * q] = v.x; z[4 * q + 1] = v.y; z[4 * q + 2] = v.z; z[4 * q + 3] = v.w;
    }
    // zsq: numpy pairwise pattern (8 accumulators, rounded products, no fma)
    float m[32];
#pragma unroll
    for (int c = 0; c < 32; c++) m[c] = __fmul_rn(z[c], z[c]);
    float r[8];
#pragma unroll
    for (int j = 0; j < 8; j++)
        r[j] = __fadd_rn(__fadd_rn(__fadd_rn(m[j], m[j + 8]), m[j + 16]), m[j + 24]);
    float zsq = __fadd_rn(
        __fadd_rn(__fadd_rn(r[0], r[1]), __fadd_rn(r[2], r[3])),
        __fadd_rn(__fadd_rn(r[4], r[5]), __fadd_rn(r[6], r[7])));

    float best = 1e30f;
    int bi = 0;
#pragma unroll 4
    for (int k = k0; k < k0 + CPK; k++) {
        const float* wr = emb + (size_t)k * 32;  // wave-uniform -> s_load
        float dot = 0.f;
#pragma unroll
        for (int c = 0; c < 32; c++) dot = __builtin_fmaf(z[c], wr[c], dot);
        float d = __fsub_rn(__fadd_rn(zsq, wsq[k]), __fmul_rn(2.f, dot));
        if (d < best) { best = d; bi = k; }  // strict < keeps first (lowest k)
    }
    cand_d[(size_t)ks * T + tok] = best;
    cand_i[(size_t)ks * T + tok] = bi;
}

// ---------------- combine: reduce KS candidates, gather winning code row ----
__global__ void __launch_bounds__(256) combine_kernel(
    const float* __restrict__ cand_d, const int* __restrict__ cand_i,
    const float* __restrict__ emb, float* __restrict__ zq, int T, int KS) {
    int tid = blockIdx.x * 256 + threadIdx.x;
    if (tid >= T * 32) return;
    int t = tid >> 5, c = tid & 31;
    float best = cand_d[t];
    int bi = cand_i[t];
    for (int s = 1; s < KS; s++) {
        float d = cand_d[(size_t)s * T + t];
        int i = cand_i[(size_t)s * T + t];
        if (d < best || (d == best && i < bi)) { best = d; bi = i; }
    }
    zq[(size_t)t * 32 + c] = emb[(size_t)bi * 32 + c];
}

// ---------------- apply: upsample + accumulate out + successive z_rest ------
// block = one (b,c) plane of 256 pixels.
template <int PN, int PN_NEXT>
__global__ void __launch_bounds__(256) apply_kernel(
    const float* __restrict__ zrest_in, const float* __restrict__ zq,
    float* __restrict__ out_lvl, const float* __restrict__ out_prev,
    float* __restrict__ zrest_out, float* __restrict__ zflat_next) {
    __shared__ float rest[PLANE];
    int bc = blockIdx.x;
    int b = bc >> 5, c = bc & 31;
    int t = threadIdx.x;
    int h = t >> 4, w = t & 15;

    float zup;
    if constexpr (PN == 16) {
        zup = zq[(size_t)(((b * 16 + h) * 16 + w)) * 32 + c];
    } else {
        // jax resizes H first then W: make H (a) the inner contraction
        float wy[4], wx[4];
        int iy0, ny, jx0, nx;
        taps<PN>(h, wy, iy0, ny);
        taps<PN>(w, wx, jx0, nx);
        zup = 0.f;
        for (int e = 0; e < nx; e++) {
            float colacc = 0.f;
            for (int a = 0; a < ny; a++)
                colacc += wy[a] * zq[(size_t)((b * PN + iy0 + a) * PN + (jx0 + e)) * 32 + c];
            zup += wx[e] * colacc;
        }
    }
    int idx = bc * PLANE + t;
    float prev = out_prev ? out_prev[idx] : 0.f;
    out_lvl[idx] = __fadd_rn(prev, zup);   // z_dec = z_dec + z_up (ref order)

    if (zflat_next) {
        // z_rest = z_rest - z_up (successive subtraction, ref order)
        float rv = __fsub_rn(zrest_in[idx], zup);
        rest[t] = rv;
        if (zrest_out) zrest_out[idx] = rv;
        __syncthreads();
        constexpr int S = 16 / PN_NEXT;
        if (t < PN_NEXT * PN_NEXT) {
            int i = t / PN_NEXT, j = t % PN_NEXT;
            float s = 0.f;
            for (int di = 0; di < S; di++)          // row-major sequential,
                for (int dj = 0; dj < S; dj++)      // numpy strided-reduce order
                    s = __fadd_rn(s, rest[(i * S + di) * 16 + (j * S + dj)]);
            zflat_next[(size_t)((b * PN_NEXT + i) * PN_NEXT + j) * 32 + c] =
                s * (1.f / (float)(S * S));         // /2^k exact
        }
    }
}

extern "C" void kernel_launch(void* const* d_in, const int* in_sizes, int n_in,
                              void* d_out, int out_size, void* d_ws, size_t ws_size,
                              hipStream_t stream) {
    const float* z_enc = (const float*)d_in[0];   // [64,32,16,16]
    const float* emb   = (const float*)d_in[1];   // [4096,32]
    float* out = (float*)d_out;                   // [5,64,32,16,16]
    float* ws = (float*)d_ws;

    float* wsq    = ws;                       // 4096
    float* zflat  = wsq + NK;                 // 524288 (token-major, C-last)
    float* zq     = zflat + 524288;           // 524288
    float* zrest  = zq + 524288;              // 524288 (plane layout)
    float* cand_d = zrest + 524288;           // 131072
    int*   cand_i = (int*)(cand_d + 131072);  // 131072

    const int LVL = NB * NC * PLANE;  // 524288 elems per output level

    init_kernel<<<2048, 256, 0, stream>>>(z_enc, emb, zflat, wsq);

    // level 0: PN=1, T=64, KS=64, CPK=64
    part_kernel<<<dim3(1, 64), 64, 0, stream>>>(zflat, emb, wsq, cand_d, cand_i, 64, 64);
    combine_kernel<<<8, 256, 0, stream>>>(cand_d, cand_i, emb, zq, 64, 64);
    apply_kernel<1, 2><<<2048, 256, 0, stream>>>(z_enc, zq, out, nullptr, zrest, zflat);

    // level 1: PN=2, T=256, KS=32, CPK=128
    part_kernel<<<dim3(4, 32), 64, 0, stream>>>(zflat, emb, wsq, cand_d, cand_i, 256, 128);
    combine_kernel<<<32, 256, 0, stream>>>(cand_d, cand_i, emb, zq, 256, 32);
    apply_kernel<2, 4><<<2048, 256, 0, stream>>>(zrest, zq, out + LVL, out, zrest, zflat);

    // level 2: PN=4, T=1024, KS=16, CPK=256
    part_kernel<<<dim3(16, 16), 64, 0, stream>>>(zflat, emb, wsq, cand_d, cand_i, 1024, 256);
    combine_kernel<<<128, 256, 0, stream>>>(cand_d, cand_i, emb, zq, 1024, 16);
    apply_kernel<4, 8><<<2048, 256, 0, stream>>>(zrest, zq, out + 2 * LVL, out + LVL, zrest, zflat);

    // level 3: PN=8, T=4096, KS=16, CPK=256
    part_kernel<<<dim3(64, 16), 64, 0, stream>>>(zflat, emb, wsq, cand_d, cand_i, 4096, 256);
    combine_kernel<<<512, 256, 0, stream>>>(cand_d, cand_i, emb, zq, 4096, 16);
    apply_kernel<8, 16><<<2048, 256, 0, stream>>>(zrest, zq, out + 3 * LVL, out + 2 * LVL, zrest, zflat);

    // level 4: PN=16, T=16384, KS=8, CPK=512 (identity down+up)
    part_kernel<<<dim3(256, 8), 64, 0, stream>>>(zflat, emb, wsq, cand_d, cand_i, 16384, 512);
    combine_kernel<<<2048, 256, 0, stream>>>(cand_d, cand_i, emb, zq, 16384, 8);
    apply_kernel<16, 16><<<2048, 256, 0, stream>>>(zrest, zq, out + 4 * LVL, out + 3 * LVL, nullptr, nullptr);
}

// Round 3
// 358.318 us; speedup vs baseline: 1.1914x; 1.1914x over previous
//
#include <hip/hip_runtime.h>

#define NB 64      // batch
#define NC 32      // channels
#define PLANE 256  // 16*16
#define NK 4096    // codebook size

// ---------------- cubic (Keys a=-0.5), matches jax.image.resize 'cubic' ----
__device__ __forceinline__ float cubic_w(float x) {
    x = fabsf(x);
    if (x >= 2.f) return 0.f;
    if (x >= 1.f) return ((-0.5f * x + 2.5f) * x - 4.f) * x + 2.f;
    return ((1.5f * x - 2.5f) * x) * x + 1.f;
}

template <int PN>
__device__ __forceinline__ void taps(int o, float* w, int& i0, int& n) {
    float sf = (o + 0.5f) * ((float)PN / 16.f) - 0.5f;
    int lo = (int)floorf(sf) - 1;
    int hi = lo + 3;
    if (lo < 0) lo = 0;
    if (hi > PN - 1) hi = PN - 1;
    n = hi - lo + 1;
    i0 = lo;
    float tot = 0.f;
    for (int i = 0; i < n; i++) {
        float ww = cubic_w(sf - (float)(lo + i));
        w[i] = ww;
        tot += ww;
    }
    float inv = 1.f / tot;
    for (int i = 0; i < n; i++) w[i] *= inv;
}

// ---- exact-order helpers (match numpy reference rounding; do not touch) ----
#define FMA4(D, A, B)                                                          \
    D = __builtin_fmaf((A).x, (B).x, D); D = __builtin_fmaf((A).y, (B).y, D);  \
    D = __builtin_fmaf((A).z, (B).z, D); D = __builtin_fmaf((A).w, (B).w, D)
#define DOT32(D)                                                               \
    FMA4(D, z0, w0); FMA4(D, z1, w1); FMA4(D, z2, w2); FMA4(D, z3, w3);        \
    FMA4(D, z4, w4); FMA4(D, z5, w5); FMA4(D, z6, w6); FMA4(D, z7, w7)

__device__ __forceinline__ float pairwise_zsq(float4 z0, float4 z1, float4 z2,
                                              float4 z3, float4 z4, float4 z5,
                                              float4 z6, float4 z7) {
#define SQ_(a) __fmul_rn((a), (a))
#define R4_(a, b, c, d) \
    __fadd_rn(__fadd_rn(__fadd_rn(SQ_(a), SQ_(b)), SQ_(c)), SQ_(d))
    float r0 = R4_(z0.x, z2.x, z4.x, z6.x);
    float r1 = R4_(z0.y, z2.y, z4.y, z6.y);
    float r2 = R4_(z0.z, z2.z, z4.z, z6.z);
    float r3 = R4_(z0.w, z2.w, z4.w, z6.w);
    float r4 = R4_(z1.x, z3.x, z5.x, z7.x);
    float r5 = R4_(z1.y, z3.y, z5.y, z7.y);
    float r6 = R4_(z1.z, z3.z, z5.z, z7.z);
    float r7 = R4_(z1.w, z3.w, z5.w, z7.w);
    return __fadd_rn(__fadd_rn(__fadd_rn(r0, r1), __fadd_rn(r2, r3)),
                     __fadd_rn(__fadd_rn(r4, r5), __fadd_rn(r6, r7)));
#undef R4_
#undef SQ_
}

// ---------------- init: plane means of z_enc -> zflat0 ; ||e||^2 -----------
__global__ void __launch_bounds__(256) init_kernel(
    const float* __restrict__ z_enc, const float* __restrict__ emb,
    float* __restrict__ zflat0, float* __restrict__ wsq) {
    int bc = blockIdx.x;
    int t = threadIdx.x;
    float v = z_enc[bc * PLANE + t];
    for (int o = 32; o > 0; o >>= 1) v += __shfl_down(v, o, 64);
    __shared__ float p[4];
    if ((t & 63) == 0) p[t >> 6] = v;
    __syncthreads();
    if (t == 0) zflat0[bc] = (p[0] + p[1] + p[2] + p[3]) * (1.f / 256.f);
    if (t < 64) {
        int k = 2 * bc + (t >> 5);
        int c = t & 31;
        float e = emb[k * 32 + c];
        float s = __fmul_rn(e, e);
        for (int o = 16; o > 0; o >>= 1) s += __shfl_down(s, o, 32);
        if (c == 0) wsq[k] = s;
    }
}

// ---------------- token-parallel argmin partial (large T) -------------------
// 1 wave = 64 tokens; k-loop wave-uniform -> emb rows come in as s_loads.
// dist = fl(fl(zsq+wsq[k]) - 2*dot), dot = sequential fp32 fma chain (c=0..31)
// exactly like the numpy reference -> same rounding grid, same ties.
__global__ void __launch_bounds__(64, 4) part_kernel(
    const float* __restrict__ zflat, const float* __restrict__ emb,
    const float* __restrict__ wsq, float* __restrict__ cand_d,
    int* __restrict__ cand_i, int T, int CPK) {
    int tok = blockIdx.x * 64 + threadIdx.x;
    int k0 = blockIdx.y * CPK;
    const float4* zr = (const float4*)(zflat + (size_t)tok * 32);
    float4 z0 = zr[0], z1 = zr[1], z2 = zr[2], z3 = zr[3];
    float4 z4 = zr[4], z5 = zr[5], z6 = zr[6], z7 = zr[7];
    float zsq = pairwise_zsq(z0, z1, z2, z3, z4, z5, z6, z7);

    float best = 1e30f;
    int bi = 0;
#pragma unroll 4
    for (int k = k0; k < k0 + CPK; k++) {
        const float4* wr = (const float4*)emb + (size_t)k * 8;  // uniform
        float4 w0 = wr[0], w1 = wr[1], w2 = wr[2], w3 = wr[3];
        float4 w4 = wr[4], w5 = wr[5], w6 = wr[6], w7 = wr[7];
        float dot = 0.f;
        DOT32(dot);
        float d = __fsub_rn(__fadd_rn(zsq, wsq[k]), __fmul_rn(2.f, dot));
        if (d < best) { best = d; bi = k; }  // strict < keeps lowest k
    }
    cand_d[(size_t)blockIdx.y * T + tok] = best;
    cand_i[(size_t)blockIdx.y * T + tok] = bi;
}

// ---------------- k-parallel argmin partial (small T: levels 0,1) -----------
// 1 wave = 1 token x 64*KPL codes; lane L handles k = kbase + j*64 + L.
// Same exact per-k dist; wave shuffle-reduce of lexicographic (d, k) min.
template <int KPL>
__global__ void __launch_bounds__(64, 4) partk_kernel(
    const float* __restrict__ zflat, const float* __restrict__ emb,
    const float* __restrict__ wsq, float* __restrict__ cand_d,
    int* __restrict__ cand_i, int T) {
    int tok = blockIdx.x;
    int lane = threadIdx.x;
    int kbase = blockIdx.y * (KPL * 64);
    const float4* zr = (const float4*)(zflat + (size_t)tok * 32);
    float4 z0 = zr[0], z1 = zr[1], z2 = zr[2], z3 = zr[3];
    float4 z4 = zr[4], z5 = zr[5], z6 = zr[6], z7 = zr[7];
    float zsq = pairwise_zsq(z0, z1, z2, z3, z4, z5, z6, z7);

    float best = 1e30f;
    int bi = 0;
#pragma unroll
    for (int j = 0; j < KPL; j++) {
        int k = kbase + j * 64 + lane;   // ascending per lane
        const float4* wr = (const float4*)emb + (size_t)k * 8;  // per-lane
        float4 w0 = wr[0], w1 = wr[1], w2 = wr[2], w3 = wr[3];
        float4 w4 = wr[4], w5 = wr[5], w6 = wr[6], w7 = wr[7];
        float dot = 0.f;
        DOT32(dot);
        float d = __fsub_rn(__fadd_rn(zsq, wsq[k]), __fmul_rn(2.f, dot));
        if (d < best) { best = d; bi = k; }
    }
    // lexicographic (d, k) min across the wave (first-index tie-break)
    for (int off = 32; off > 0; off >>= 1) {
        float od = __shfl_down(best, off, 64);
        int oi = __shfl_down(bi, off, 64);
        if (od < best || (od == best && oi < bi)) { best = od; bi = oi; }
    }
    if (lane == 0) {
        cand_d[(size_t)blockIdx.y * T + tok] = best;
        cand_i[(size_t)blockIdx.y * T + tok] = bi;
    }
}

// ---------------- combine: reduce KS candidates, gather winning code row ----
__global__ void __launch_bounds__(256) combine_kernel(
    const float* __restrict__ cand_d, const int* __restrict__ cand_i,
    const float* __restrict__ emb, float* __restrict__ zq, int T, int KS) {
    int tid = blockIdx.x * 256 + threadIdx.x;
    if (tid >= T * 32) return;
    int t = tid >> 5, c = tid & 31;
    float best = cand_d[t];
    int bi = cand_i[t];
    for (int s = 1; s < KS; s++) {
        float d = cand_d[(size_t)s * T + t];
        int i = cand_i[(size_t)s * T + t];
        if (d < best || (d == best && i < bi)) { best = d; bi = i; }
    }
    zq[(size_t)t * 32 + c] = emb[(size_t)bi * 32 + c];
}

// ---------------- apply: upsample + accumulate out + successive z_rest ------
template <int PN, int PN_NEXT>
__global__ void __launch_bounds__(256) apply_kernel(
    const float* __restrict__ zrest_in, const float* __restrict__ zq,
    float* __restrict__ out_lvl, const float* __restrict__ out_prev,
    float* __restrict__ zrest_out, float* __restrict__ zflat_next) {
    __shared__ float rest[PLANE];
    int bc = blockIdx.x;
    int b = bc >> 5, c = bc & 31;
    int t = threadIdx.x;
    int h = t >> 4, w = t & 15;

    float zup;
    if constexpr (PN == 16) {
        zup = zq[(size_t)(((b * 16 + h) * 16 + w)) * 32 + c];
    } else {
        float wy[4], wx[4];
        int iy0, ny, jx0, nx;
        taps<PN>(h, wy, iy0, ny);
        taps<PN>(w, wx, jx0, nx);
        zup = 0.f;
        for (int e = 0; e < nx; e++) {
            float colacc = 0.f;
            for (int a = 0; a < ny; a++)
                colacc += wy[a] * zq[(size_t)((b * PN + iy0 + a) * PN + (jx0 + e)) * 32 + c];
            zup += wx[e] * colacc;
        }
    }
    int idx = bc * PLANE + t;
    float prev = out_prev ? out_prev[idx] : 0.f;
    out_lvl[idx] = __fadd_rn(prev, zup);

    if (zflat_next) {
        float rv = __fsub_rn(zrest_in[idx], zup);
        rest[t] = rv;
        if (zrest_out) zrest_out[idx] = rv;
        __syncthreads();
        constexpr int S = 16 / PN_NEXT;
        if (t < PN_NEXT * PN_NEXT) {
            int i = t / PN_NEXT, j = t % PN_NEXT;
            float s = 0.f;
            for (int di = 0; di < S; di++)
                for (int dj = 0; dj < S; dj++)
                    s = __fadd_rn(s, rest[(i * S + di) * 16 + (j * S + dj)]);
            zflat_next[(size_t)((b * PN_NEXT + i) * PN_NEXT + j) * 32 + c] =
                s * (1.f / (float)(S * S));
        }
    }
}

extern "C" void kernel_launch(void* const* d_in, const int* in_sizes, int n_in,
                              void* d_out, int out_size, void* d_ws, size_t ws_size,
                              hipStream_t stream) {
    const float* z_enc = (const float*)d_in[0];   // [64,32,16,16]
    const float* emb   = (const float*)d_in[1];   // [4096,32]
    float* out = (float*)d_out;                   // [5,64,32,16,16]
    float* ws = (float*)d_ws;

    float* wsq    = ws;                       // 4096
    float* zflat  = wsq + NK;                 // 524288 (token-major, C-last)
    float* zq     = zflat + 524288;           // 524288
    float* zrest  = zq + 524288;              // 524288 (plane layout)
    float* cand_d = zrest + 524288;           // 524288
    int*   cand_i = (int*)(cand_d + 524288);  // 524288

    const int LVL = NB * NC * PLANE;  // 524288 elems per output level

    init_kernel<<<2048, 256, 0, stream>>>(z_enc, emb, zflat, wsq);

    // level 0: T=64, k-parallel: 16 chunks x 256 codes -> 1024 waves
    partk_kernel<4><<<dim3(64, 16), 64, 0, stream>>>(zflat, emb, wsq, cand_d, cand_i, 64);
    combine_kernel<<<8, 256, 0, stream>>>(cand_d, cand_i, emb, zq, 64, 16);
    apply_kernel<1, 2><<<2048, 256, 0, stream>>>(z_enc, zq, out, nullptr, zrest, zflat);

    // level 1: T=256, k-parallel: 4096 waves
    partk_kernel<4><<<dim3(256, 16), 64, 0, stream>>>(zflat, emb, wsq, cand_d, cand_i, 256);
    combine_kernel<<<32, 256, 0, stream>>>(cand_d, cand_i, emb, zq, 256, 16);
    apply_kernel<2, 4><<<2048, 256, 0, stream>>>(zrest, zq, out + LVL, out, zrest, zflat);

    // level 2: T=1024, token-parallel, KS=128, CPK=32 -> 2048 waves
    part_kernel<<<dim3(16, 128), 64, 0, stream>>>(zflat, emb, wsq, cand_d, cand_i, 1024, 32);
    combine_kernel<<<128, 256, 0, stream>>>(cand_d, cand_i, emb, zq, 1024, 128);
    apply_kernel<4, 8><<<2048, 256, 0, stream>>>(zrest, zq, out + 2 * LVL, out + LVL, zrest, zflat);

    // level 3: T=4096, KS=64, CPK=64 -> 4096 waves
    part_kernel<<<dim3(64, 64), 64, 0, stream>>>(zflat, emb, wsq, cand_d, cand_i, 4096, 64);
    combine_kernel<<<512, 256, 0, stream>>>(cand_d, cand_i, emb, zq, 4096, 64);
    apply_kernel<8, 16><<<2048, 256, 0, stream>>>(zrest, zq, out + 3 * LVL, out + 2 * LVL, zrest, zflat);

    // level 4: T=16384, KS=32, CPK=128 -> 8192 waves (full occupancy)
    part_kernel<<<dim3(256, 32), 64, 0, stream>>>(zflat, emb, wsq, cand_d, cand_i, 16384, 128);
    combine_kernel<<<2048, 256, 0, stream>>>(cand_d, cand_i, emb, zq, 16384, 32);
    apply_kernel<16, 16><<<2048, 256, 0, stream>>>(zrest, zq, out + 4 * LVL, out + 3 * LVL, nullptr, nullptr);
}